// Round 2
// baseline (1048.504 us; speedup 1.0000x reference)
//
#include <hip/hip_runtime.h>
#include <hip/hip_bf16.h>
#include <stdint.h>
#include <type_traits>

#define NHEAD  16
#define DMODEL 1024
#define BATCH  2
#define SEQ    2048
#define DH     64
#define MROWS  (BATCH*SEQ)   // 4096

typedef __attribute__((ext_vector_type(8))) short bf16x8;
typedef __attribute__((ext_vector_type(4))) float f32x4;

__device__ inline short f2bs(float f) {
    __hip_bfloat16 h = __float2bfloat16(f);
    return *reinterpret_cast<short*>(&h);
}

// ---------------- GEMM: C[M,N] = A[M,K] @ W[N,K]^T + bias[N] ----------------
// A: fp32 or bf16; W,bias: fp32; C: fp32 or bf16. bf16 MFMA, fp32 accumulate.
// 128x128 tile, BK=32, 256 threads = 4 waves in 2x2, each wave 64x64 via 4x4 frags.
#define LDK 40   // padded LDS row stride (shorts): bank stride 20 -> 2-way (free)

template <typename TA, typename TC>
__global__ __launch_bounds__(256)
void gemm_nt_bias(const TA* __restrict__ A,
                  const float* __restrict__ W,
                  const float* __restrict__ bias,
                  TC* __restrict__ C)
{
    const int N = DMODEL, K = DMODEL;
    __shared__ short As[128 * LDK];
    __shared__ short Bs[128 * LDK];

    const int t    = threadIdx.x;
    const int lane = t & 63;
    const int w    = t >> 6;
    const int wm   = (w >> 1) * 64;
    const int wn   = (w & 1) * 64;
    const int bm   = blockIdx.y * 128;
    const int bn   = blockIdx.x * 128;
    const int quad = lane >> 4;
    const int l16  = lane & 15;
    const int srow = t >> 1;          // 0..127
    const int scol = (t & 1) * 16;    // 0 or 16

    f32x4 acc[4][4];
#pragma unroll
    for (int i = 0; i < 4; i++)
#pragma unroll
        for (int j = 0; j < 4; j++)
            acc[i][j] = (f32x4){0.f, 0.f, 0.f, 0.f};

    for (int kt = 0; kt < K; kt += 32) {
        short aT[16], wT[16];
        // ---- fetch A row-slice (16 elems), convert to bf16 if needed ----
        if constexpr (std::is_same<TA, float>::value) {
            const float* ap = A + (size_t)(bm + srow) * K + kt + scol;
            float fb[16];
            *(float4*)&fb[0]  = *(const float4*)(ap + 0);
            *(float4*)&fb[4]  = *(const float4*)(ap + 4);
            *(float4*)&fb[8]  = *(const float4*)(ap + 8);
            *(float4*)&fb[12] = *(const float4*)(ap + 12);
#pragma unroll
            for (int i = 0; i < 16; i++) aT[i] = f2bs(fb[i]);
        } else {
            const __hip_bfloat16* ap = (const __hip_bfloat16*)A + (size_t)(bm + srow) * K + kt + scol;
            *(uint4*)&aT[0] = *(const uint4*)(ap);
            *(uint4*)&aT[8] = *(const uint4*)(ap + 8);
        }
        // ---- fetch W row-slice (always fp32) ----
        {
            const float* wp = W + (size_t)(bn + srow) * K + kt + scol;
            float fb[16];
            *(float4*)&fb[0]  = *(const float4*)(wp + 0);
            *(float4*)&fb[4]  = *(const float4*)(wp + 4);
            *(float4*)&fb[8]  = *(const float4*)(wp + 8);
            *(float4*)&fb[12] = *(const float4*)(wp + 12);
#pragma unroll
            for (int i = 0; i < 16; i++) wT[i] = f2bs(fb[i]);
        }
        __syncthreads();   // prev iteration's fragment reads done
        *(uint4*)&As[srow * LDK + scol]     = *(uint4*)&aT[0];
        *(uint4*)&As[srow * LDK + scol + 8] = *(uint4*)&aT[8];
        *(uint4*)&Bs[srow * LDK + scol]     = *(uint4*)&wT[0];
        *(uint4*)&Bs[srow * LDK + scol + 8] = *(uint4*)&wT[8];
        __syncthreads();

        bf16x8 af[4], bf[4];
#pragma unroll
        for (int mi = 0; mi < 4; mi++)
            af[mi] = *(const bf16x8*)&As[(wm + mi * 16 + l16) * LDK + quad * 8];
#pragma unroll
        for (int ni = 0; ni < 4; ni++)
            bf[ni] = *(const bf16x8*)&Bs[(wn + ni * 16 + l16) * LDK + quad * 8];
#pragma unroll
        for (int mi = 0; mi < 4; mi++)
#pragma unroll
            for (int ni = 0; ni < 4; ni++)
                acc[mi][ni] = __builtin_amdgcn_mfma_f32_16x16x32_bf16(
                    af[mi], bf[ni], acc[mi][ni], 0, 0, 0);
    }

    // epilogue: C/D layout col=lane&15, row=quad*4+r
#pragma unroll
    for (int mi = 0; mi < 4; mi++) {
#pragma unroll
        for (int ni = 0; ni < 4; ni++) {
            const int row0 = bm + wm + mi * 16 + quad * 4;
            const int col  = bn + wn + ni * 16 + l16;
            const float bb = bias[col];
#pragma unroll
            for (int r = 0; r < 4; r++) {
                const float val = acc[mi][ni][r] + bb;
                if constexpr (std::is_same<TC, float>::value)
                    C[(size_t)(row0 + r) * N + col] = val;
                else
                    C[(size_t)(row0 + r) * N + col] = __float2bfloat16(val);
            }
        }
    }
}

// ---------------- Flash-style causal attention (vector fp32) ----------------
// block = (b, h, q-tile of 64 rows); 256 threads as 16x16, each owns a 4x4 micro-tile.
// qp/kp/vp/ao are bf16 workspace buffers.
#define ALD 65   // padded fp32 LDS stride

__global__ __launch_bounds__(256)
void attn_causal(const __hip_bfloat16* __restrict__ qp,
                 const __hip_bfloat16* __restrict__ kp,
                 const __hip_bfloat16* __restrict__ vp,
                 __hip_bfloat16* __restrict__ ao)
{
    __shared__ float Qs[64 * ALD];
    __shared__ float Ks[64 * ALD];
    __shared__ float Vs[64 * ALD];
    __shared__ float Ss[64 * ALD];
    __shared__ float m_s[64], l_s[64], al_s[64];

    const int t  = threadIdx.x;
    const int qt = blockIdx.x;       // q tile 0..31
    const int bh = blockIdx.y;       // 0..31
    const int b  = bh >> 4;
    const int h  = bh & 15;
    const int ty = t >> 4, tx = t & 15;
    const int lr = t >> 2, lc = (t & 3) * 16;   // staging: 4 threads/row, 16 elems each

    // ---- load Q tile [64 x 64] -> fp32 LDS ----
    {
        const __hip_bfloat16* g = qp + ((size_t)(b * SEQ + qt * 64 + lr)) * DMODEL + h * DH + lc;
        uint4 u0 = *(const uint4*)g;
        uint4 u1 = *(const uint4*)(g + 8);
        const unsigned short* p0 = (const unsigned short*)&u0;
        const unsigned short* p1 = (const unsigned short*)&u1;
        float* dst = &Qs[lr * ALD + lc];
#pragma unroll
        for (int i = 0; i < 8; i++) dst[i]     = __uint_as_float(((unsigned)p0[i]) << 16);
#pragma unroll
        for (int i = 0; i < 8; i++) dst[8 + i] = __uint_as_float(((unsigned)p1[i]) << 16);
    }
    if (t < 64) { m_s[t] = -__builtin_inff(); l_s[t] = 0.f; }
    float o[4][4];
#pragma unroll
    for (int r = 0; r < 4; r++)
#pragma unroll
        for (int c = 0; c < 4; c++) o[r][c] = 0.f;
    __syncthreads();

    for (int jt = 0; jt <= qt; ++jt) {
        // ---- load K, V tiles ----
        {
            const size_t rb = ((size_t)(b * SEQ + jt * 64 + lr)) * DMODEL + h * DH + lc;
            uint4 k0 = *(const uint4*)(kp + rb);
            uint4 k1 = *(const uint4*)(kp + rb + 8);
            uint4 v0 = *(const uint4*)(vp + rb);
            uint4 v1 = *(const uint4*)(vp + rb + 8);
            const unsigned short* pk0 = (const unsigned short*)&k0;
            const unsigned short* pk1 = (const unsigned short*)&k1;
            const unsigned short* pv0 = (const unsigned short*)&v0;
            const unsigned short* pv1 = (const unsigned short*)&v1;
            float* dk = &Ks[lr * ALD + lc];
            float* dv = &Vs[lr * ALD + lc];
#pragma unroll
            for (int i = 0; i < 8; i++) {
                dk[i]     = __uint_as_float(((unsigned)pk0[i]) << 16);
                dk[8 + i] = __uint_as_float(((unsigned)pk1[i]) << 16);
                dv[i]     = __uint_as_float(((unsigned)pv0[i]) << 16);
                dv[8 + i] = __uint_as_float(((unsigned)pv1[i]) << 16);
            }
        }
        __syncthreads();

        // ---- S = Q K^T (each thread 4x4) ----
        float s[4][4];
#pragma unroll
        for (int r = 0; r < 4; r++)
#pragma unroll
            for (int c = 0; c < 4; c++) s[r][c] = 0.f;
#pragma unroll 8
        for (int k = 0; k < 64; k++) {
            float a0 = Qs[(ty * 4 + 0) * ALD + k];
            float a1 = Qs[(ty * 4 + 1) * ALD + k];
            float a2 = Qs[(ty * 4 + 2) * ALD + k];
            float a3 = Qs[(ty * 4 + 3) * ALD + k];
            float c0 = Ks[(tx * 4 + 0) * ALD + k];
            float c1 = Ks[(tx * 4 + 1) * ALD + k];
            float c2 = Ks[(tx * 4 + 2) * ALD + k];
            float c3 = Ks[(tx * 4 + 3) * ALD + k];
            s[0][0] += a0 * c0; s[0][1] += a0 * c1; s[0][2] += a0 * c2; s[0][3] += a0 * c3;
            s[1][0] += a1 * c0; s[1][1] += a1 * c1; s[1][2] += a1 * c2; s[1][3] += a1 * c3;
            s[2][0] += a2 * c0; s[2][1] += a2 * c1; s[2][2] += a2 * c2; s[2][3] += a2 * c3;
            s[3][0] += a3 * c0; s[3][1] += a3 * c1; s[3][2] += a3 * c2; s[3][3] += a3 * c3;
        }
        // scale by 1/sqrt(d_model)=1/32, causal mask, store to Ss
#pragma unroll
        for (int r = 0; r < 4; r++) {
#pragma unroll
            for (int c = 0; c < 4; c++) {
                const int gi = qt * 64 + ty * 4 + r;
                const int gj = jt * 64 + tx * 4 + c;
                const float val = (gj <= gi) ? s[r][c] * 0.03125f : -__builtin_inff();
                Ss[(ty * 4 + r) * ALD + tx * 4 + c] = val;
            }
        }
        __syncthreads();

        // ---- online softmax over this tile (one thread per row) ----
        if (t < 64) {
            const float mo = m_s[t];
            float mx = mo;
            for (int j = 0; j < 64; j++) mx = fmaxf(mx, Ss[t * ALD + j]);
            const float al = __expf(mo - mx);   // mo=-inf -> 0
            float sum = 0.f;
            for (int j = 0; j < 64; j++) {
                const float p = __expf(Ss[t * ALD + j] - mx);
                Ss[t * ALD + j] = p;
                sum += p;
            }
            m_s[t]  = mx;
            l_s[t]  = al * l_s[t] + sum;
            al_s[t] = al;
        }
        __syncthreads();

        // ---- O = alpha*O + P V ----
#pragma unroll
        for (int r = 0; r < 4; r++) {
            const float al = al_s[ty * 4 + r];
#pragma unroll
            for (int c = 0; c < 4; c++) o[r][c] *= al;
        }
#pragma unroll 8
        for (int k = 0; k < 64; k++) {
            float p0 = Ss[(ty * 4 + 0) * ALD + k];
            float p1 = Ss[(ty * 4 + 1) * ALD + k];
            float p2 = Ss[(ty * 4 + 2) * ALD + k];
            float p3 = Ss[(ty * 4 + 3) * ALD + k];
            float v0 = Vs[k * ALD + tx * 4 + 0];
            float v1 = Vs[k * ALD + tx * 4 + 1];
            float v2 = Vs[k * ALD + tx * 4 + 2];
            float v3 = Vs[k * ALD + tx * 4 + 3];
            o[0][0] += p0 * v0; o[0][1] += p0 * v1; o[0][2] += p0 * v2; o[0][3] += p0 * v3;
            o[1][0] += p1 * v0; o[1][1] += p1 * v1; o[1][2] += p1 * v2; o[1][3] += p1 * v3;
            o[2][0] += p2 * v0; o[2][1] += p2 * v1; o[2][2] += p2 * v2; o[2][3] += p2 * v3;
            o[3][0] += p3 * v0; o[3][1] += p3 * v1; o[3][2] += p3 * v2; o[3][3] += p3 * v3;
        }
        __syncthreads();   // protect Ks/Vs/Ss before next tile
    }

    // ---- normalize + write [64 x 64] tile of ao (bf16) ----
#pragma unroll
    for (int r = 0; r < 4; r++) {
        const int row = ty * 4 + r;
        const float inv = 1.f / l_s[row];
        const size_t base = ((size_t)(b * SEQ + qt * 64 + row)) * DMODEL + h * DH;
#pragma unroll
        for (int c = 0; c < 4; c++)
            ao[base + tx * 4 + c] = __float2bfloat16(o[r][c] * inv);
    }
}

// ---------------- launch ----------------
extern "C" void kernel_launch(void* const* d_in, const int* in_sizes, int n_in,
                              void* d_out, int out_size, void* d_ws, size_t ws_size,
                              hipStream_t stream) {
    const float* q  = (const float*)d_in[0];
    const float* k  = (const float*)d_in[1];
    const float* v  = (const float*)d_in[2];
    const float* Wq = (const float*)d_in[3];
    const float* bq = (const float*)d_in[4];
    const float* Wk = (const float*)d_in[5];
    const float* bk = (const float*)d_in[6];
    const float* Wv = (const float*)d_in[7];
    const float* bv = (const float*)d_in[8];
    const float* Wo = (const float*)d_in[9];
    const float* bo = (const float*)d_in[10];
    float* out = (float*)d_out;

    const size_t nelem = (size_t)MROWS * DMODEL;   // 4 Mi elems = 8 MB bf16 each
    __hip_bfloat16* qp = (__hip_bfloat16*)d_ws;
    __hip_bfloat16* kp = qp + nelem;
    __hip_bfloat16* vp = kp + nelem;
    __hip_bfloat16* ao = vp + nelem;

    dim3 gg(DMODEL / 128, MROWS / 128);  // (8, 32)
    dim3 bb(256);
    hipLaunchKernelGGL((gemm_nt_bias<float, __hip_bfloat16>), gg, bb, 0, stream, q, Wq, bq, qp);
    hipLaunchKernelGGL((gemm_nt_bias<float, __hip_bfloat16>), gg, bb, 0, stream, k, Wk, bk, kp);
    hipLaunchKernelGGL((gemm_nt_bias<float, __hip_bfloat16>), gg, bb, 0, stream, v, Wv, bv, vp);

    dim3 ga(SEQ / 64, BATCH * NHEAD);    // (32, 32)
    hipLaunchKernelGGL(attn_causal, ga, bb, 0, stream, qp, kp, vp, ao);

    hipLaunchKernelGGL((gemm_nt_bias<__hip_bfloat16, float>), gg, bb, 0, stream, ao, Wo, bo, out);
}

// Round 3
// 424.776 us; speedup vs baseline: 2.4684x; 2.4684x over previous
//
#include <hip/hip_runtime.h>
#include <hip/hip_bf16.h>
#include <stdint.h>
#include <type_traits>

#define NHEAD  16
#define DMODEL 1024
#define BATCH  2
#define SEQ    2048
#define DH     64
#define MROWS  (BATCH*SEQ)   // 4096

typedef __attribute__((ext_vector_type(8))) short bf16x8;
typedef __attribute__((ext_vector_type(4))) float f32x4;

__device__ inline short f2bs(float f) {
    __hip_bfloat16 h = __float2bfloat16(f);
    return *reinterpret_cast<short*>(&h);
}

// ---------------- GEMM: C[M,N] = A[M,K] @ W[N,K]^T + bias[N] ----------------
// A: fp32 or bf16; W,bias: fp32; C: fp32 or bf16. bf16 MFMA, fp32 accumulate.
// (unchanged from R2 — verified correct)
#define LDK 40

template <typename TA, typename TC>
__global__ __launch_bounds__(256)
void gemm_nt_bias(const TA* __restrict__ A,
                  const float* __restrict__ W,
                  const float* __restrict__ bias,
                  TC* __restrict__ C)
{
    const int N = DMODEL, K = DMODEL;
    __shared__ short As[128 * LDK];
    __shared__ short Bs[128 * LDK];

    const int t    = threadIdx.x;
    const int lane = t & 63;
    const int w    = t >> 6;
    const int wm   = (w >> 1) * 64;
    const int wn   = (w & 1) * 64;
    const int bm   = blockIdx.y * 128;
    const int bn   = blockIdx.x * 128;
    const int quad = lane >> 4;
    const int l16  = lane & 15;
    const int srow = t >> 1;
    const int scol = (t & 1) * 16;

    f32x4 acc[4][4];
#pragma unroll
    for (int i = 0; i < 4; i++)
#pragma unroll
        for (int j = 0; j < 4; j++)
            acc[i][j] = (f32x4){0.f, 0.f, 0.f, 0.f};

    for (int kt = 0; kt < K; kt += 32) {
        short aT[16], wT[16];
        if constexpr (std::is_same<TA, float>::value) {
            const float* ap = A + (size_t)(bm + srow) * K + kt + scol;
            float fb[16];
            *(float4*)&fb[0]  = *(const float4*)(ap + 0);
            *(float4*)&fb[4]  = *(const float4*)(ap + 4);
            *(float4*)&fb[8]  = *(const float4*)(ap + 8);
            *(float4*)&fb[12] = *(const float4*)(ap + 12);
#pragma unroll
            for (int i = 0; i < 16; i++) aT[i] = f2bs(fb[i]);
        } else {
            const __hip_bfloat16* ap = (const __hip_bfloat16*)A + (size_t)(bm + srow) * K + kt + scol;
            *(uint4*)&aT[0] = *(const uint4*)(ap);
            *(uint4*)&aT[8] = *(const uint4*)(ap + 8);
        }
        {
            const float* wp = W + (size_t)(bn + srow) * K + kt + scol;
            float fb[16];
            *(float4*)&fb[0]  = *(const float4*)(wp + 0);
            *(float4*)&fb[4]  = *(const float4*)(wp + 4);
            *(float4*)&fb[8]  = *(const float4*)(wp + 8);
            *(float4*)&fb[12] = *(const float4*)(wp + 12);
#pragma unroll
            for (int i = 0; i < 16; i++) wT[i] = f2bs(fb[i]);
        }
        __syncthreads();
        *(uint4*)&As[srow * LDK + scol]     = *(uint4*)&aT[0];
        *(uint4*)&As[srow * LDK + scol + 8] = *(uint4*)&aT[8];
        *(uint4*)&Bs[srow * LDK + scol]     = *(uint4*)&wT[0];
        *(uint4*)&Bs[srow * LDK + scol + 8] = *(uint4*)&wT[8];
        __syncthreads();

        bf16x8 af[4], bf[4];
#pragma unroll
        for (int mi = 0; mi < 4; mi++)
            af[mi] = *(const bf16x8*)&As[(wm + mi * 16 + l16) * LDK + quad * 8];
#pragma unroll
        for (int ni = 0; ni < 4; ni++)
            bf[ni] = *(const bf16x8*)&Bs[(wn + ni * 16 + l16) * LDK + quad * 8];
#pragma unroll
        for (int mi = 0; mi < 4; mi++)
#pragma unroll
            for (int ni = 0; ni < 4; ni++)
                acc[mi][ni] = __builtin_amdgcn_mfma_f32_16x16x32_bf16(
                    af[mi], bf[ni], acc[mi][ni], 0, 0, 0);
    }

#pragma unroll
    for (int mi = 0; mi < 4; mi++) {
#pragma unroll
        for (int ni = 0; ni < 4; ni++) {
            const int row0 = bm + wm + mi * 16 + quad * 4;
            const int col  = bn + wn + ni * 16 + l16;
            const float bb = bias[col];
#pragma unroll
            for (int r = 0; r < 4; r++) {
                const float val = acc[mi][ni][r] + bb;
                if constexpr (std::is_same<TC, float>::value)
                    C[(size_t)(row0 + r) * N + col] = val;
                else
                    C[(size_t)(row0 + r) * N + col] = __float2bfloat16(val);
            }
        }
    }
}

// ---------------- MFMA flash causal attention ----------------
// block = (b, h, 64-row q tile); 256 thr = 4 waves; wave w owns q-rows [16w,16w+16).
// All tiles bf16 in LDS. S = Q K^T and O += P V via mfma_f32_16x16x32_bf16.
// P round-trips through LDS wave-locally (no barrier). 2 barriers per KV tile.
#define LQK 72   // row stride (shorts) for Qs/Ks/Vt: 144B -> bank stride 4, 2-way on frag reads
#define LPS 68   // row stride for Ps: 136B -> bank stride 2

__global__ __launch_bounds__(256, 4)
void attn_causal_mfma(const __hip_bfloat16* __restrict__ qp,
                      const __hip_bfloat16* __restrict__ kp,
                      const __hip_bfloat16* __restrict__ vp,
                      __hip_bfloat16* __restrict__ ao)
{
    __shared__ short Qs[64 * LQK];
    __shared__ short Ks[64 * LQK];
    __shared__ short Vt[64 * LQK];   // V transposed: [dh][key]
    __shared__ short Ps[64 * LPS];

    const int t    = threadIdx.x;
    const int lane = t & 63;
    const int w    = t >> 6;
    const int l16  = lane & 15;
    const int quad = lane >> 4;
    const int qt   = blockIdx.x;      // q tile 0..31
    const int bh   = blockIdx.y;      // 0..31
    const int b    = bh >> 4;
    const int h    = bh & 15;
    const int lr   = t >> 2;          // staging row 0..63
    const int lc   = (t & 3) * 16;    // staging col {0,16,32,48}

    const size_t headoff = (size_t)h * DH;

    // ---- stage Q tile (each wave stages exactly its own 16 rows: lr in [16w,16w+16)) ----
    {
        const __hip_bfloat16* g = qp + ((size_t)(b * SEQ + qt * 64 + lr)) * DMODEL + headoff + lc;
        *(uint4*)&Qs[lr * LQK + lc]     = *(const uint4*)g;
        *(uint4*)&Qs[lr * LQK + lc + 8] = *(const uint4*)(g + 8);
    }
    // wave-local write->read: compiler inserts lgkmcnt wait, no barrier needed
    bf16x8 aq0 = *(const bf16x8*)&Qs[(16 * w + l16) * LQK + quad * 8];
    bf16x8 aq1 = *(const bf16x8*)&Qs[(16 * w + l16) * LQK + quad * 8 + 32];

    float m[4], l[4];
    f32x4 oc[4];
#pragma unroll
    for (int r = 0; r < 4; r++) { m[r] = -__builtin_inff(); l[r] = 0.f; }
#pragma unroll
    for (int dt = 0; dt < 4; dt++) oc[dt] = (f32x4){0.f, 0.f, 0.f, 0.f};

    for (int jt = 0; jt <= qt; ++jt) {
        // ---- prefetch K/V rows from global into regs ----
        const size_t rb = ((size_t)(b * SEQ + jt * 64 + lr)) * DMODEL + headoff + lc;
        uint4 k0 = *(const uint4*)(kp + rb);
        uint4 k1 = *(const uint4*)(kp + rb + 8);
        uint4 v0 = *(const uint4*)(vp + rb);
        uint4 v1 = *(const uint4*)(vp + rb + 8);
        __syncthreads();   // prior tile's Ks/Vt reads complete
        *(uint4*)&Ks[lr * LQK + lc]     = k0;
        *(uint4*)&Ks[lr * LQK + lc + 8] = k1;
        {
            const unsigned short* pv0 = (const unsigned short*)&v0;
            const unsigned short* pv1 = (const unsigned short*)&v1;
#pragma unroll
            for (int i = 0; i < 8; i++) {
                Vt[(lc + i) * LQK + lr]     = (short)pv0[i];
                Vt[(lc + 8 + i) * LQK + lr] = (short)pv1[i];
            }
        }
        __syncthreads();

        // ---- S = Q K^T : wave computes 16x64 slab as 4 col tiles ----
        f32x4 sc[4];
#pragma unroll
        for (int ct = 0; ct < 4; ct++) {
            bf16x8 bk0 = *(const bf16x8*)&Ks[(16 * ct + l16) * LQK + quad * 8];
            bf16x8 bk1 = *(const bf16x8*)&Ks[(16 * ct + l16) * LQK + quad * 8 + 32];
            sc[ct] = __builtin_amdgcn_mfma_f32_16x16x32_bf16(
                aq0, bk0, (f32x4){0.f, 0.f, 0.f, 0.f}, 0, 0, 0);
            sc[ct] = __builtin_amdgcn_mfma_f32_16x16x32_bf16(aq1, bk1, sc[ct], 0, 0, 0);
        }

        // ---- scale + causal mask (C layout: row = quad*4+r, col = 16ct+l16) ----
        float p[4][4];
        const bool diag = (jt == qt);
#pragma unroll
        for (int ct = 0; ct < 4; ct++) {
#pragma unroll
            for (int r = 0; r < 4; r++) {
                float v = sc[ct][r] * 0.03125f;
                if (diag && (16 * ct + l16 > 16 * w + quad * 4 + r)) v = -__builtin_inff();
                p[ct][r] = v;
            }
        }

        // ---- online softmax per row r (row spread across 16 lanes of same quad) ----
        float alpha[4];
#pragma unroll
        for (int r = 0; r < 4; r++) {
            float mx = fmaxf(fmaxf(p[0][r], p[1][r]), fmaxf(p[2][r], p[3][r]));
#pragma unroll
            for (int d = 1; d < 16; d <<= 1) mx = fmaxf(mx, __shfl_xor(mx, d));
            const float mn = fmaxf(m[r], mx);
            alpha[r] = __expf(m[r] - mn);
            float sum = 0.f;
#pragma unroll
            for (int ct = 0; ct < 4; ct++) {
                p[ct][r] = __expf(p[ct][r] - mn);
                sum += p[ct][r];
            }
#pragma unroll
            for (int d = 1; d < 16; d <<= 1) sum += __shfl_xor(sum, d);
            l[r] = alpha[r] * l[r] + sum;
            m[r] = mn;
        }

        // ---- write P to LDS (wave-local rows), reload as A fragments ----
#pragma unroll
        for (int ct = 0; ct < 4; ct++)
#pragma unroll
            for (int r = 0; r < 4; r++)
                Ps[(16 * w + quad * 4 + r) * LPS + 16 * ct + l16] = f2bs(p[ct][r]);
        bf16x8 ap0 = *(const bf16x8*)&Ps[(16 * w + l16) * LPS + quad * 8];
        bf16x8 ap1 = *(const bf16x8*)&Ps[(16 * w + l16) * LPS + quad * 8 + 32];

        // ---- rescale O, then O += P V ----
#pragma unroll
        for (int dt = 0; dt < 4; dt++)
#pragma unroll
            for (int r = 0; r < 4; r++) oc[dt][r] *= alpha[r];
#pragma unroll
        for (int dt = 0; dt < 4; dt++) {
            bf16x8 bv0 = *(const bf16x8*)&Vt[(16 * dt + l16) * LQK + quad * 8];
            bf16x8 bv1 = *(const bf16x8*)&Vt[(16 * dt + l16) * LQK + quad * 8 + 32];
            oc[dt] = __builtin_amdgcn_mfma_f32_16x16x32_bf16(ap0, bv0, oc[dt], 0, 0, 0);
            oc[dt] = __builtin_amdgcn_mfma_f32_16x16x32_bf16(ap1, bv1, oc[dt], 0, 0, 0);
        }
    }

    // ---- normalize + write (C layout) ----
#pragma unroll
    for (int r = 0; r < 4; r++) {
        const float inv = 1.f / l[r];
        const size_t base = ((size_t)(b * SEQ + qt * 64 + 16 * w + quad * 4 + r)) * DMODEL + headoff;
#pragma unroll
        for (int dt = 0; dt < 4; dt++)
            ao[base + 16 * dt + l16] = __float2bfloat16(oc[dt][r] * inv);
    }
}

// ---------------- launch ----------------
extern "C" void kernel_launch(void* const* d_in, const int* in_sizes, int n_in,
                              void* d_out, int out_size, void* d_ws, size_t ws_size,
                              hipStream_t stream) {
    const float* q  = (const float*)d_in[0];
    const float* k  = (const float*)d_in[1];
    const float* v  = (const float*)d_in[2];
    const float* Wq = (const float*)d_in[3];
    const float* bq = (const float*)d_in[4];
    const float* Wk = (const float*)d_in[5];
    const float* bk = (const float*)d_in[6];
    const float* Wv = (const float*)d_in[7];
    const float* bv = (const float*)d_in[8];
    const float* Wo = (const float*)d_in[9];
    const float* bo = (const float*)d_in[10];
    float* out = (float*)d_out;

    const size_t nelem = (size_t)MROWS * DMODEL;   // 8 MB bf16 each
    __hip_bfloat16* qp = (__hip_bfloat16*)d_ws;
    __hip_bfloat16* kp = qp + nelem;
    __hip_bfloat16* vp = kp + nelem;
    __hip_bfloat16* ao = vp + nelem;

    dim3 gg(DMODEL / 128, MROWS / 128);  // (8, 32)
    dim3 bb(256);
    hipLaunchKernelGGL((gemm_nt_bias<float, __hip_bfloat16>), gg, bb, 0, stream, q, Wq, bq, qp);
    hipLaunchKernelGGL((gemm_nt_bias<float, __hip_bfloat16>), gg, bb, 0, stream, k, Wk, bk, kp);
    hipLaunchKernelGGL((gemm_nt_bias<float, __hip_bfloat16>), gg, bb, 0, stream, v, Wv, bv, vp);

    dim3 ga(SEQ / 64, BATCH * NHEAD);    // (32, 32)
    hipLaunchKernelGGL(attn_causal_mfma, ga, bb, 0, stream, qp, kp, vp, ao);

    hipLaunchKernelGGL((gemm_nt_bias<__hip_bfloat16, float>), gg, bb, 0, stream, ao, Wo, bo, out);
}